// Round 1
// baseline (570.703 us; speedup 1.0000x reference)
//
#include <hip/hip_runtime.h>

#define L2E 1.4426950408889634f
#define LN2 0.6931471805599453f
#define NEG (-1e30f)

constexpr int Bc = 16, Tc = 160, Uc = 80, U1 = 81, Vc = 512, DD = 240;
// ws layout (floats): blankD [16][240][81], labD [16][240][81], loss [16], counter [1 int]
// blankD[b][s][u] = blank_lp[b][t][u] with s=t+u ; labD[b][s][u] = lab_lp[b][t][u]

__device__ __forceinline__ float laddexp(float a, float b) {
    float m = fmaxf(a, b);
    float d = fminf(a, b) - m;                       // <= 0
    float e = __builtin_amdgcn_exp2f(d * L2E);       // exp(d)
    return fmaf(LN2, __builtin_amdgcn_logf(1.0f + e), m);  // m + log1p(e)
}

// One wave per TWO (b,t,u) rows of 512 logits: 4 float4 loads in flight,
// two interleaved butterfly reductions (ILP), anti-diagonal layout writes.
__global__ __launch_bounds__(256) void k_lse(const float* __restrict__ logits,
                                             const int* __restrict__ targets,
                                             float* __restrict__ blankD,
                                             float* __restrict__ labD,
                                             int* __restrict__ counter) {
    if (blockIdx.x == 0 && threadIdx.x == 0) *counter = 0;  // for fused k_dp tail
    const int lane = threadIdx.x & 63;
    const int wid  = threadIdx.x >> 6;
    const int r0   = blockIdx.x * 8 + wid * 2;      // wave owns rows r0, r0+1

    const float4* __restrict__ bp =
        reinterpret_cast<const float4*>(logits + (size_t)r0 * Vc);
    const float4 a0 = bp[lane];                     // row0 floats [4l, 4l+3]
    const float4 a1 = bp[lane + 64];                // row0 floats [256+4l, ...]
    const float4 b0 = bp[lane + 128];               // row1 floats [4l, ...]
    const float4 b1 = bp[lane + 192];               // row1 floats [256+4l, ...]

    float m0 = fmaxf(fmaxf(fmaxf(a0.x, a0.y), fmaxf(a0.z, a0.w)),
                     fmaxf(fmaxf(a1.x, a1.y), fmaxf(a1.z, a1.w)));
    float m1 = fmaxf(fmaxf(fmaxf(b0.x, b0.y), fmaxf(b0.z, b0.w)),
                     fmaxf(fmaxf(b1.x, b1.y), fmaxf(b1.z, b1.w)));
#pragma unroll
    for (int o = 32; o; o >>= 1) {
        m0 = fmaxf(m0, __shfl_xor(m0, o));
        m1 = fmaxf(m1, __shfl_xor(m1, o));
    }
    const float k0 = m0 * L2E, k1 = m1 * L2E;
    float s0 = __builtin_amdgcn_exp2f(fmaf(a0.x, L2E, -k0))
             + __builtin_amdgcn_exp2f(fmaf(a0.y, L2E, -k0))
             + __builtin_amdgcn_exp2f(fmaf(a0.z, L2E, -k0))
             + __builtin_amdgcn_exp2f(fmaf(a0.w, L2E, -k0))
             + __builtin_amdgcn_exp2f(fmaf(a1.x, L2E, -k0))
             + __builtin_amdgcn_exp2f(fmaf(a1.y, L2E, -k0))
             + __builtin_amdgcn_exp2f(fmaf(a1.z, L2E, -k0))
             + __builtin_amdgcn_exp2f(fmaf(a1.w, L2E, -k0));
    float s1 = __builtin_amdgcn_exp2f(fmaf(b0.x, L2E, -k1))
             + __builtin_amdgcn_exp2f(fmaf(b0.y, L2E, -k1))
             + __builtin_amdgcn_exp2f(fmaf(b0.z, L2E, -k1))
             + __builtin_amdgcn_exp2f(fmaf(b0.w, L2E, -k1))
             + __builtin_amdgcn_exp2f(fmaf(b1.x, L2E, -k1))
             + __builtin_amdgcn_exp2f(fmaf(b1.y, L2E, -k1))
             + __builtin_amdgcn_exp2f(fmaf(b1.z, L2E, -k1))
             + __builtin_amdgcn_exp2f(fmaf(b1.w, L2E, -k1));
#pragma unroll
    for (int o = 32; o; o >>= 1) {
        s0 += __shfl_xor(s0, o);
        s1 += __shfl_xor(s1, o);
    }

    const float bl0 = __shfl(a1.w, 63);             // row0[511] — no reload needed
    const float bl1 = __shfl(b1.w, 63);             // row1[511]
    if (lane < 2) {
        const int r = r0 + lane;
        const float m = lane ? m1 : m0;
        const float s = lane ? s1 : s0;
        const float blank_logit = lane ? bl1 : bl0;
        const float lse = fmaf(LN2, __builtin_amdgcn_logf(s), m);
        const int u  = r % U1;
        const int bt = r / U1;
        const int t  = bt % Tc;
        const int b  = bt / Tc;
        const size_t idx = ((size_t)b * DD + (t + u)) * U1 + u;
        blankD[idx] = blank_logit - lse;
        if (u < Uc) {                               // label gather: row line is L1-hot
            labD[idx] = logits[(size_t)r * Vc + targets[b * Uc + u]] - lse;
        }
    }
}

// One wave per batch: anti-diagonal wavefront DP fully in registers.
// lane l owns u0=2l and u1=2l+1; alpha[t][u-1] comes via one __shfl_up.
// Final mean fused in via last-block atomic counter.
__global__ __launch_bounds__(64) void k_dp(const float* __restrict__ blankD,
                                           const float* __restrict__ labD,
                                           const int* __restrict__ llen,
                                           const int* __restrict__ tlen,
                                           float* __restrict__ loss,
                                           int* __restrict__ counter,
                                           float* __restrict__ out) {
    const int b    = blockIdx.x;
    const int lane = threadIdx.x;
    const int u0 = 2 * lane, u1 = u0 + 1;
    const bool v0 = (u0 <= Uc), v1 = (u1 <= Uc);
    const int cu0  = v0 ? u0 : Uc;                  // clamped (in-bounds) addresses
    const int cu1  = v1 ? u1 : Uc;
    const int cu0m = (cu0 >= 1) ? (cu0 - 1) : 0;

    const float* __restrict__ bl = blankD + (size_t)b * DD * U1;
    const float* __restrict__ la = labD  + (size_t)b * DD * U1;
    const int tl = llen[b], ul = tlen[b];
    const int d_end = tl - 1 + ul;                  // in [119, 239]
    const float end_blank = bl[(size_t)d_end * U1 + ul];  // hoisted out of the loop
    const int lane_e = ul >> 1;                     // lane+slot holding alpha[.][ul]
    const int slot1  = ul & 1;

    float a0 = (u0 == 0) ? 0.0f : NEG;              // alpha on diagonal d=0
    float a1 = NEG;
    float res = NEG;

    // register prefetch buffers, depth 8 (one diagonal group)
    float pb0[8], pb1[8], pl0[8], pl1[8];
#pragma unroll
    for (int k = 0; k < 8; ++k) {                   // data s=0..7 for d=1..8
        pb0[k] = bl[k * U1 + cu0];
        pb1[k] = bl[k * U1 + cu1];
        pl0[k] = la[k * U1 + cu0m];
        pl1[k] = la[k * U1 + cu0];
    }

    for (int g = 0; g < 30; ++g) {
        const int dbase = 1 + g * 8;
        float nb0[8], nb1[8], nl0[8], nl1[8];
#pragma unroll
        for (int k = 0; k < 8; ++k) {               // prefetch next group's diagonals
            int s = dbase + 7 + k;
            if (s > DD - 1) s = DD - 1;             // clamp: values unused, address safe
            nb0[k] = bl[s * U1 + cu0];
            nb1[k] = bl[s * U1 + cu1];
            nl0[k] = la[s * U1 + cu0m];
            nl1[k] = la[s * U1 + cu0];
        }
#pragma unroll
        for (int k = 0; k < 8; ++k) {
            const int d = dbase + k;
            const float a1m = __shfl_up(a1, 1);     // old alpha at u0-1 (diag d-1)
            const int t0 = d - u0, t1 = d - u1;
            float top0 = (t0 >= 1) ? (a0 + pb0[k]) : NEG;
            float lef0 = (u0 >= 1) ? (a1m + pl0[k]) : NEG;
            float top1 = (t1 >= 1) ? (a1 + pb1[k]) : NEG;
            float lef1 = a0 + pl1[k];               // u1 >= 1 always
            float na0 = laddexp(top0, lef0);
            float na1 = laddexp(top1, lef1);
            na0 = (v0 && t0 >= 0 && t0 < Tc) ? na0 : NEG;
            na1 = (v1 && t1 >= 0 && t1 < Tc) ? na1 : NEG;
            a0 = na0; a1 = na1;
            if (d == d_end) {                       // uniform compare, no load
                const float av = slot1 ? a1 : a0;
                if (lane == lane_e) res = av + end_blank;
            }
        }
#pragma unroll
        for (int k = 0; k < 8; ++k) {
            pb0[k] = nb0[k]; pb1[k] = nb1[k]; pl0[k] = nl0[k]; pl1[k] = nl1[k];
        }
    }

    if (lane == lane_e) loss[b] = -res;
    __threadfence();                                // release loss[b] device-wide
    if (lane == 0) {
        const int old = __hip_atomic_fetch_add(counter, 1, __ATOMIC_ACQ_REL,
                                               __HIP_MEMORY_SCOPE_AGENT);
        if (old == Bc - 1) {                        // last block: deterministic mean
            float s = 0.0f;
#pragma unroll
            for (int i = 0; i < Bc; ++i) s += loss[i];
            out[0] = s * (1.0f / Bc);
        }
    }
}

extern "C" void kernel_launch(void* const* d_in, const int* in_sizes, int n_in,
                              void* d_out, int out_size, void* d_ws, size_t ws_size,
                              hipStream_t stream) {
    const float* logits  = (const float*)d_in[0];
    const int*   targets = (const int*)d_in[1];
    const int*   llen    = (const int*)d_in[2];
    const int*   tlen    = (const int*)d_in[3];

    float* ws     = (float*)d_ws;
    float* blankD = ws;
    float* labD   = ws + (size_t)Bc * DD * U1;          // +311040
    float* loss   = labD + (size_t)Bc * DD * U1;        // +311040
    int*   counter = (int*)(loss + Bc);
    float* out    = (float*)d_out;

    const int nrows = Bc * Tc * U1;                     // 207360, divisible by 8
    k_lse<<<dim3(nrows / 8), dim3(256), 0, stream>>>(logits, targets, blankD, labD, counter);
    k_dp<<<dim3(Bc), dim3(64), 0, stream>>>(blankD, labD, llen, tlen, loss, counter, out);
}

// Round 2
// 536.348 us; speedup vs baseline: 1.0641x; 1.0641x over previous
//
#include <hip/hip_runtime.h>

#define L2E 1.4426950408889634f
#define LN2 0.6931471805599453f
#define NEG (-1e30f)

constexpr int Bc = 16, Tc = 160, Uc = 80, U1 = 81, Vc = 512, DD = 240;
// ws layout (floats): blankD [16][240][81], labD [16][240][81], loss [16], counter [1 int]
// blankD[b][s][u] = blank_lp[b][t][u] with s=t+u ; labD[b][s][u] = lab_lp[b][t][u]
// Rows with t >= llen[b] or u > tlen[b] are DEAD: the DP recurrence only moves
// (t,u)->(t+1,u)/(t,u+1), so unwritten (poisoned) cells never reach the endpoint.

__device__ __forceinline__ float laddexp(float a, float b) {
    float m = fmaxf(a, b);
    float d = fminf(a, b) - m;                       // <= 0
    float e = __builtin_amdgcn_exp2f(d * L2E);       // exp(d)
    return fmaf(LN2, __builtin_amdgcn_logf(1.0f + e), m);  // m + log1p(e)
}

// One wave per TWO (b,t,u) rows of 512 logits. Dead rows (outside the per-batch
// valid rectangle) are skipped wave-uniformly BEFORE their loads issue: ~41% of
// the logits read volume disappears.
__global__ __launch_bounds__(256) void k_lse(const float* __restrict__ logits,
                                             const int* __restrict__ targets,
                                             const int* __restrict__ llen,
                                             const int* __restrict__ tlen,
                                             float* __restrict__ blankD,
                                             float* __restrict__ labD,
                                             int* __restrict__ counter) {
    if (blockIdx.x == 0 && threadIdx.x == 0) *counter = 0;  // for fused k_dp tail
    const int lane = threadIdx.x & 63;
    const int wid  = threadIdx.x >> 6;
    const int r0   = blockIdx.x * 8 + wid * 2;      // wave owns rows r0, r0+1
    const int r1   = r0 + 1;

    // wave-uniform row coords (scalar arithmetic + s_loads)
    const int u_0 = r0 % U1, bt_0 = r0 / U1, t_0 = bt_0 % Tc, b_0 = bt_0 / Tc;
    const int u_1 = r1 % U1, bt_1 = r1 / U1, t_1 = bt_1 % Tc, b_1 = bt_1 / Tc;
    const bool valid0 = (t_0 < llen[b_0]) && (u_0 <= tlen[b_0]);
    const bool valid1 = (t_1 < llen[b_1]) && (u_1 <= tlen[b_1]);
    if (!valid0 && !valid1) return;                 // wave-uniform early out

    const float4* __restrict__ bp =
        reinterpret_cast<const float4*>(logits + (size_t)r0 * Vc);
    float4 a0 = {0.f, 0.f, 0.f, 0.f}, a1 = {0.f, 0.f, 0.f, 0.f};
    float4 c0 = {0.f, 0.f, 0.f, 0.f}, c1 = {0.f, 0.f, 0.f, 0.f};
    if (valid0) {                                   // wave-uniform branch: no divergence
        a0 = bp[lane];                              // row0 floats [4l, 4l+3]
        a1 = bp[lane + 64];                         // row0 floats [256+4l, ...]
    }
    if (valid1) {
        c0 = bp[lane + 128];                        // row1 floats [4l, ...]
        c1 = bp[lane + 192];                        // row1 floats [256+4l, ...]
    }

    float m0 = fmaxf(fmaxf(fmaxf(a0.x, a0.y), fmaxf(a0.z, a0.w)),
                     fmaxf(fmaxf(a1.x, a1.y), fmaxf(a1.z, a1.w)));
    float m1 = fmaxf(fmaxf(fmaxf(c0.x, c0.y), fmaxf(c0.z, c0.w)),
                     fmaxf(fmaxf(c1.x, c1.y), fmaxf(c1.z, c1.w)));
#pragma unroll
    for (int o = 32; o; o >>= 1) {
        m0 = fmaxf(m0, __shfl_xor(m0, o));
        m1 = fmaxf(m1, __shfl_xor(m1, o));
    }
    const float k0 = m0 * L2E, k1 = m1 * L2E;
    float s0 = __builtin_amdgcn_exp2f(fmaf(a0.x, L2E, -k0))
             + __builtin_amdgcn_exp2f(fmaf(a0.y, L2E, -k0))
             + __builtin_amdgcn_exp2f(fmaf(a0.z, L2E, -k0))
             + __builtin_amdgcn_exp2f(fmaf(a0.w, L2E, -k0))
             + __builtin_amdgcn_exp2f(fmaf(a1.x, L2E, -k0))
             + __builtin_amdgcn_exp2f(fmaf(a1.y, L2E, -k0))
             + __builtin_amdgcn_exp2f(fmaf(a1.z, L2E, -k0))
             + __builtin_amdgcn_exp2f(fmaf(a1.w, L2E, -k0));
    float s1 = __builtin_amdgcn_exp2f(fmaf(c0.x, L2E, -k1))
             + __builtin_amdgcn_exp2f(fmaf(c0.y, L2E, -k1))
             + __builtin_amdgcn_exp2f(fmaf(c0.z, L2E, -k1))
             + __builtin_amdgcn_exp2f(fmaf(c0.w, L2E, -k1))
             + __builtin_amdgcn_exp2f(fmaf(c1.x, L2E, -k1))
             + __builtin_amdgcn_exp2f(fmaf(c1.y, L2E, -k1))
             + __builtin_amdgcn_exp2f(fmaf(c1.z, L2E, -k1))
             + __builtin_amdgcn_exp2f(fmaf(c1.w, L2E, -k1));
#pragma unroll
    for (int o = 32; o; o >>= 1) {
        s0 += __shfl_xor(s0, o);
        s1 += __shfl_xor(s1, o);
    }

    const float bl0 = __shfl(a1.w, 63);             // row0[511] — no reload needed
    const float bl1 = __shfl(c1.w, 63);             // row1[511]
    if (lane < 2) {
        const bool valid = lane ? valid1 : valid0;
        if (valid) {
            const int r = r0 + lane;
            const float m = lane ? m1 : m0;
            const float s = lane ? s1 : s0;
            const float blank_logit = lane ? bl1 : bl0;
            const float lse = fmaf(LN2, __builtin_amdgcn_logf(s), m);
            const int u = lane ? u_1 : u_0;
            const int t = lane ? t_1 : t_0;
            const int b = lane ? b_1 : b_0;
            const size_t idx = ((size_t)b * DD + (t + u)) * U1 + u;
            blankD[idx] = blank_logit - lse;
            if (u < Uc) {                           // label gather: row line is cache-hot
                labD[idx] = logits[(size_t)r * Vc + targets[b * Uc + u]] - lse;
            }
        }
    }
}

// One wave per batch: anti-diagonal wavefront DP fully in registers.
// lane l owns u0=2l and u1=2l+1; alpha[t][u-1] comes via one __shfl_up.
// Final mean fused in via last-block atomic counter.
__global__ __launch_bounds__(64) void k_dp(const float* __restrict__ blankD,
                                           const float* __restrict__ labD,
                                           const int* __restrict__ llen,
                                           const int* __restrict__ tlen,
                                           float* __restrict__ loss,
                                           int* __restrict__ counter,
                                           float* __restrict__ out) {
    const int b    = blockIdx.x;
    const int lane = threadIdx.x;
    const int u0 = 2 * lane, u1 = u0 + 1;
    const bool v0 = (u0 <= Uc), v1 = (u1 <= Uc);
    const int cu0  = v0 ? u0 : Uc;                  // clamped (in-bounds) addresses
    const int cu1  = v1 ? u1 : Uc;
    const int cu0m = (cu0 >= 1) ? (cu0 - 1) : 0;

    const float* __restrict__ bl = blankD + (size_t)b * DD * U1;
    const float* __restrict__ la = labD  + (size_t)b * DD * U1;
    const int tl = llen[b], ul = tlen[b];
    const int d_end = tl - 1 + ul;                  // in [119, 239]
    const float end_blank = bl[(size_t)d_end * U1 + ul];  // hoisted out of the loop
    const int lane_e = ul >> 1;                     // lane+slot holding alpha[.][ul]
    const int slot1  = ul & 1;

    float a0 = (u0 == 0) ? 0.0f : NEG;              // alpha on diagonal d=0
    float a1 = NEG;
    float res = NEG;

    // register prefetch buffers, depth 8 (one diagonal group)
    float pb0[8], pb1[8], pl0[8], pl1[8];
#pragma unroll
    for (int k = 0; k < 8; ++k) {                   // data s=0..7 for d=1..8
        pb0[k] = bl[k * U1 + cu0];
        pb1[k] = bl[k * U1 + cu1];
        pl0[k] = la[k * U1 + cu0m];
        pl1[k] = la[k * U1 + cu0];
    }

    for (int g = 0; g < 30; ++g) {
        const int dbase = 1 + g * 8;
        float nb0[8], nb1[8], nl0[8], nl1[8];
#pragma unroll
        for (int k = 0; k < 8; ++k) {               // prefetch next group's diagonals
            int s = dbase + 7 + k;
            if (s > DD - 1) s = DD - 1;             // clamp: values unused, address safe
            nb0[k] = bl[s * U1 + cu0];
            nb1[k] = bl[s * U1 + cu1];
            nl0[k] = la[s * U1 + cu0m];
            nl1[k] = la[s * U1 + cu0];
        }
#pragma unroll
        for (int k = 0; k < 8; ++k) {
            const int d = dbase + k;
            const float a1m = __shfl_up(a1, 1);     // old alpha at u0-1 (diag d-1)
            const int t0 = d - u0, t1 = d - u1;
            float top0 = (t0 >= 1) ? (a0 + pb0[k]) : NEG;
            float lef0 = (u0 >= 1) ? (a1m + pl0[k]) : NEG;
            float top1 = (t1 >= 1) ? (a1 + pb1[k]) : NEG;
            float lef1 = a0 + pl1[k];               // u1 >= 1 always
            float na0 = laddexp(top0, lef0);
            float na1 = laddexp(top1, lef1);
            na0 = (v0 && t0 >= 0 && t0 < Tc) ? na0 : NEG;
            na1 = (v1 && t1 >= 0 && t1 < Tc) ? na1 : NEG;
            a0 = na0; a1 = na1;
            if (d == d_end) {                       // uniform compare, no load
                const float av = slot1 ? a1 : a0;
                if (lane == lane_e) res = av + end_blank;
            }
        }
#pragma unroll
        for (int k = 0; k < 8; ++k) {
            pb0[k] = nb0[k]; pb1[k] = nb1[k]; pl0[k] = nl0[k]; pl1[k] = nl1[k];
        }
    }

    if (lane == lane_e) loss[b] = -res;
    __threadfence();                                // release loss[b] device-wide
    if (lane == 0) {
        const int old = __hip_atomic_fetch_add(counter, 1, __ATOMIC_ACQ_REL,
                                               __HIP_MEMORY_SCOPE_AGENT);
        if (old == Bc - 1) {                        // last block: deterministic mean
            float s = 0.0f;
#pragma unroll
            for (int i = 0; i < Bc; ++i) s += loss[i];
            out[0] = s * (1.0f / Bc);
        }
    }
}

extern "C" void kernel_launch(void* const* d_in, const int* in_sizes, int n_in,
                              void* d_out, int out_size, void* d_ws, size_t ws_size,
                              hipStream_t stream) {
    const float* logits  = (const float*)d_in[0];
    const int*   targets = (const int*)d_in[1];
    const int*   llen    = (const int*)d_in[2];
    const int*   tlen    = (const int*)d_in[3];

    float* ws     = (float*)d_ws;
    float* blankD = ws;
    float* labD   = ws + (size_t)Bc * DD * U1;          // +311040
    float* loss   = labD + (size_t)Bc * DD * U1;        // +311040
    int*   counter = (int*)(loss + Bc);
    float* out    = (float*)d_out;

    const int nrows = Bc * Tc * U1;                     // 207360, divisible by 8
    k_lse<<<dim3(nrows / 8), dim3(256), 0, stream>>>(logits, targets, llen, tlen,
                                                     blankD, labD, counter);
    k_dp<<<dim3(Bc), dim3(64), 0, stream>>>(blankD, labD, llen, tlen, loss, counter, out);
}